// Round 1
// baseline (852.599 us; speedup 1.0000x reference)
//
#include <hip/hip_runtime.h>
#include <cmath>

#define HS 32768
#define NL 16
#define TPB 1024
#define PPT 8

typedef float fvec4 __attribute__((ext_vector_type(4)));

struct ResArr { int r[16]; };

// Fused point-major kernel: each WG owns a contiguous point chunk (PPT points per
// thread held in registers) and streams the 16 level tables through one 128 KB
// bf16-packed LDS buffer. No intermediate, no transpose pass.
__global__ __launch_bounds__(TPB, 1) void hash4d_fused_kernel(
    const float* __restrict__ coords,
    const float* __restrict__ tstamps,
    const float* __restrict__ tables,
    float* __restrict__ out,
    int npts, ResArr res)
{
    __shared__ unsigned lds_tab[HS];   // 128 KB: two bf16 feats packed per entry

    const int chunk = (npts + (int)gridDim.x - 1) / (int)gridDim.x;
    const int base  = (int)blockIdx.x * chunk;
    const int lim   = min(base + chunk, npts);
    const int tid   = (int)threadIdx.x;

    const unsigned P1 = 2654435761u, P2 = 805459861u, P3 = 3674653429u;
    const unsigned MASK4 = (HS - 1u) << 2;   // hash mask pre-shifted to byte offset

    // ---- per-point invariants: computed ONCE, reused across all 16 levels ----
    float c0[PPT], c1[PPT], c2[PPT], c3[PPT];
    bool  val[PPT];
    #pragma unroll
    for (int k = 0; k < PPT; ++k) {
        int p = base + k * TPB + tid;
        val[k] = (p < lim);
        float x = 0.0f, y = 0.0f, z = 0.0f, t = 0.0f;
        if (val[k]) {
            x = coords[3 * p + 0];
            y = coords[3 * p + 1];
            z = coords[3 * p + 2];
            t = tstamps[p];
        }
        t = fminf(fmaxf(t, 0.0f), 1.0f);
        // exact same arithmetic as reference (add, true divide) — now amortized 16x
        c0[k] = (x + 50.0f) / 100.0f;
        c1[k] = (y + 50.0f) / 100.0f;
        c2[k] = (z + 50.0f) / 100.0f;
        c3[k] = t;
    }

    float acc[PPT][8];   // accumulators for the current group of 4 levels (static idx)

    #pragma unroll
    for (int L = 0; L < NL; ++L) {
        __syncthreads();   // all reads of previous table done before overwrite
        {   // stage table L: fp32x2 -> packed bf16x2 (RNE), coalesced, conflict-free
            const float2* gt = ((const float2*)tables) + (size_t)L * HS;
            #pragma unroll 8
            for (int j = tid; j < HS; j += TPB) {
                float2 v = gt[j];
                unsigned ux = __float_as_uint(v.x);
                unsigned uy = __float_as_uint(v.y);
                unsigned rx = ux + 0x7fffu + ((ux >> 16) & 1u);
                unsigned ry = uy + 0x7fffu + ((uy >> 16) & 1u);
                // (ry & 0xffff0000) | (rx >> 16) in one v_perm_b32
                lds_tab[j] = __builtin_amdgcn_perm(ry, rx, 0x07060302u);
            }
        }
        __syncthreads();

        const float rf = (float)res.r[L];
        const int g4 = L & 3;

        #pragma unroll
        for (int k = 0; k < PPT; ++k) {
            if (!val[k]) continue;
            float s0 = c0[k] * rf, s1 = c1[k] * rf, s2 = c2[k] * rf, s3 = c3[k] * rf;
            float g0 = floorf(s0), g1 = floorf(s1), g2 = floorf(s2), g3 = floorf(s3);
            float f0 = s0 - g0, f1 = s1 - g1, f2 = s2 - g2, f3 = s3 - g3;

            // hash terms pre-shifted <<2: XOR result is directly the LDS byte offset
            unsigned a0 = ((unsigned)(int)g0) << 2;
            unsigned a1 = ((unsigned)(int)g1 * P1) << 2;
            unsigned a2 = ((unsigned)(int)g2 * P2) << 2;
            unsigned a3 = ((unsigned)(int)g3 * P3) << 2;
            unsigned b0 = a0 + 4u;
            unsigned b1 = a1 + (P1 << 2);
            unsigned b2 = a2 + (P2 << 2);
            unsigned b3 = a3 + (P3 << 2);

            // factored corner weights: w = w01[lo] * w23[hi]
            float m0 = 1.0f - f0, m1 = 1.0f - f1, m2 = 1.0f - f2, m3 = 1.0f - f3;
            float w01_0 = m0 * m1, w01_1 = f0 * m1, w01_2 = m0 * f1, w01_3 = f0 * f1;
            float w23_0 = m2 * m3, w23_1 = f2 * m3, w23_2 = m2 * f3, w23_3 = f2 * f3;

            float A = 0.0f, B = 0.0f;
            #pragma unroll
            for (int hi = 0; hi < 4; ++hi) {
                unsigned hb = ((hi & 1) ? b2 : a2) ^ ((hi & 2) ? b3 : a3);
                float whi = (hi == 0) ? w23_0 : (hi == 1) ? w23_1 : (hi == 2) ? w23_2 : w23_3;
                float ax = 0.0f, ay = 0.0f;
                #pragma unroll
                for (int lo = 0; lo < 4; ++lo) {
                    unsigned off = (hb ^ ((lo & 1) ? b0 : a0) ^ ((lo & 2) ? b1 : a1)) & MASK4;
                    float wlo = (lo == 0) ? w01_0 : (lo == 1) ? w01_1 : (lo == 2) ? w01_2 : w01_3;
                    unsigned pk = *(const unsigned*)((const char*)lds_tab + off);
                    ax = fmaf(wlo, __uint_as_float(pk << 16), ax);
                    ay = fmaf(wlo, __uint_as_float(pk & 0xffff0000u), ay);
                }
                A = fmaf(whi, ax, A);
                B = fmaf(whi, ay, B);
            }
            acc[k][2 * g4 + 0] = A;
            acc[k][2 * g4 + 1] = B;

            if (g4 == 3) {   // flush 32 B (one HBM sector) per point per 4-level group
                int p = base + k * TPB + tid;
                float* op = out + (size_t)p * 32 + (L >> 2) * 8;
                fvec4 v0 = { acc[k][0], acc[k][1], acc[k][2], acc[k][3] };
                fvec4 v1 = { acc[k][4], acc[k][5], acc[k][6], acc[k][7] };
                *(fvec4*)(op + 0) = v0;
                *(fvec4*)(op + 4) = v1;
            }
        }
    }
}

extern "C" void kernel_launch(void* const* d_in, const int* in_sizes, int n_in,
                              void* d_out, int out_size, void* d_ws, size_t ws_size,
                              hipStream_t stream) {
    const float* coords  = (const float*)d_in[0];
    const float* tstamps = (const float*)d_in[1];
    const float* tables  = (const float*)d_in[2];
    float* out = (float*)d_out;

    // resolutions computed host-side with the same double-precision exp/log as the
    // reference (keeps int() truncation bit-identical; do NOT hardcode)
    ResArr ra;
    for (int l = 0; l < 16; ++l) {
        double f = (double)l / 15.0;
        double v = exp(log(16.0) * (1.0 - f) + log(512.0) * f);
        ra.r[l] = (int)v;
    }

    int n = in_sizes[0] / 3;
    int ng = (n + TPB - 1) / TPB;
    if (ng > 256) ng = 256;
    if (ng < 1) ng = 1;

    hash4d_fused_kernel<<<ng, TPB, 0, stream>>>(coords, tstamps, tables, out, n, ra);
}

// Round 2
// 764.040 us; speedup vs baseline: 1.1159x; 1.1159x over previous
//
#include <hip/hip_runtime.h>
#include <cmath>

#define HS 32768
#define NL 16
#define TPB 1024
#define PPT 8
#define CAP (TPB * PPT)

typedef float fvec4 __attribute__((ext_vector_type(4)));

struct ResArr { int r[16]; };

// ---------------- Kernel F: fused point-major, level tables streamed through LDS.
// Flushes each 4-level group to ws[4][N][8] with fully coalesced, full-line stores.
__global__ __launch_bounds__(TPB, 1) void hash4d_fused_kernel(
    const float* __restrict__ coords,
    const float* __restrict__ tstamps,
    const float* __restrict__ tables,
    float* __restrict__ ws,       // [4][npts][8] floats
    int npts, ResArr res)
{
    __shared__ unsigned lds_tab[HS];   // 128 KB: two bf16 feats packed per entry

    const int chunk = (npts + (int)gridDim.x - 1) / (int)gridDim.x;
    const int wbase = (int)blockIdx.x * chunk;
    const int lim   = min(wbase + chunk, npts);
    const int tid   = (int)threadIdx.x;

    const unsigned P1 = 2654435761u, P2 = 805459861u, P3 = 3674653429u;
    const unsigned MASK4 = (HS - 1u) << 2;   // hash mask pre-shifted to byte offset

    for (int sbase = wbase; sbase < lim; sbase += CAP) {

        // ---- per-point invariants: computed ONCE, reused across all 16 levels ----
        float c0[PPT], c1[PPT], c2[PPT], c3[PPT];
        bool  val[PPT];
        #pragma unroll
        for (int k = 0; k < PPT; ++k) {
            int p = sbase + k * TPB + tid;
            val[k] = (p < lim);
            float x = 0.0f, y = 0.0f, z = 0.0f, t = 0.0f;
            if (val[k]) {
                x = coords[3 * p + 0];
                y = coords[3 * p + 1];
                z = coords[3 * p + 2];
                t = tstamps[p];
            }
            t = fminf(fmaxf(t, 0.0f), 1.0f);
            // exact same arithmetic as reference (add, true divide) — amortized 16x
            c0[k] = (x + 50.0f) / 100.0f;
            c1[k] = (y + 50.0f) / 100.0f;
            c2[k] = (z + 50.0f) / 100.0f;
            c3[k] = t;
        }

        float acc[PPT][8];   // current group of 4 levels (static indexing only)

        #pragma unroll
        for (int L = 0; L < NL; ++L) {
            __syncthreads();   // all reads of previous table done before overwrite
            {   // stage table L: fp32x2 -> packed bf16x2 (RNE), coalesced
                const float2* gt = ((const float2*)tables) + (size_t)L * HS;
                #pragma unroll 8
                for (int j = tid; j < HS; j += TPB) {
                    float2 v = gt[j];
                    unsigned ux = __float_as_uint(v.x);
                    unsigned uy = __float_as_uint(v.y);
                    unsigned rx = ux + 0x7fffu + ((ux >> 16) & 1u);
                    unsigned ry = uy + 0x7fffu + ((uy >> 16) & 1u);
                    lds_tab[j] = __builtin_amdgcn_perm(ry, rx, 0x07060302u);
                }
            }
            __syncthreads();

            const float rf = (float)res.r[L];
            const int g4 = L & 3;

            #pragma unroll
            for (int k = 0; k < PPT; ++k) {
                if (!val[k]) continue;
                float s0 = c0[k] * rf, s1 = c1[k] * rf, s2 = c2[k] * rf, s3 = c3[k] * rf;
                float g0 = floorf(s0), g1 = floorf(s1), g2 = floorf(s2), g3 = floorf(s3);
                float f0 = s0 - g0, f1 = s1 - g1, f2 = s2 - g2, f3 = s3 - g3;

                unsigned a0 = ((unsigned)(int)g0) << 2;
                unsigned a1 = ((unsigned)(int)g1 * P1) << 2;
                unsigned a2 = ((unsigned)(int)g2 * P2) << 2;
                unsigned a3 = ((unsigned)(int)g3 * P3) << 2;
                unsigned b0 = a0 + 4u;
                unsigned b1 = a1 + (P1 << 2);
                unsigned b2 = a2 + (P2 << 2);
                unsigned b3 = a3 + (P3 << 2);

                float m0 = 1.0f - f0, m1 = 1.0f - f1, m2 = 1.0f - f2, m3 = 1.0f - f3;
                float w01_0 = m0 * m1, w01_1 = f0 * m1, w01_2 = m0 * f1, w01_3 = f0 * f1;
                float w23_0 = m2 * m3, w23_1 = f2 * m3, w23_2 = m2 * f3, w23_3 = f2 * f3;

                float A = 0.0f, B = 0.0f;
                #pragma unroll
                for (int hi = 0; hi < 4; ++hi) {
                    unsigned hb = ((hi & 1) ? b2 : a2) ^ ((hi & 2) ? b3 : a3);
                    float whi = (hi == 0) ? w23_0 : (hi == 1) ? w23_1 : (hi == 2) ? w23_2 : w23_3;
                    float ax = 0.0f, ay = 0.0f;
                    #pragma unroll
                    for (int lo = 0; lo < 4; ++lo) {
                        unsigned off = (hb ^ ((lo & 1) ? b0 : a0) ^ ((lo & 2) ? b1 : a1)) & MASK4;
                        float wlo = (lo == 0) ? w01_0 : (lo == 1) ? w01_1 : (lo == 2) ? w01_2 : w01_3;
                        unsigned pk = *(const unsigned*)((const char*)lds_tab + off);
                        ax = fmaf(wlo, __uint_as_float(pk << 16), ax);
                        ay = fmaf(wlo, __uint_as_float(pk & 0xffff0000u), ay);
                    }
                    A = fmaf(whi, ax, A);
                    B = fmaf(whi, ay, B);
                }
                acc[k][2 * g4 + 0] = A;
                acc[k][2 * g4 + 1] = B;

                if (g4 == 3) {
                    // flush 32 B/point to ws[group][p][8] — lanes contiguous,
                    // wave covers 2 KB of fully-written lines (no partial-line RMW)
                    int p = sbase + k * TPB + tid;
                    float* wp = ws + ((size_t)(L >> 2) * npts + (size_t)p) * 8;
                    fvec4 v0 = { acc[k][0], acc[k][1], acc[k][2], acc[k][3] };
                    fvec4 v1 = { acc[k][4], acc[k][5], acc[k][6], acc[k][7] };
                    *(fvec4*)(wp + 0) = v0;
                    *(fvec4*)(wp + 4) = v1;
                }
            }
        }
    }
}

// ---------------- Kernel T2: ws[4][N][8] -> out[N][32] via swizzled LDS tile.
// Loads lane-contiguous, stores lane-contiguous (1 KB/wave), LDS conflict-free.
__global__ __launch_bounds__(256, 4) void hash4d_out_kernel(
    const float* __restrict__ ws, float* __restrict__ out, int npts)
{
    __shared__ fvec4 lt4[2048];   // 32 KB = 256 points x 32 floats
    const int tid  = (int)threadIdx.x;
    const int base = (int)blockIdx.x * 256;

    if (base + 256 <= npts) {
        #pragma unroll
        for (int g = 0; g < 4; ++g) {
            const fvec4* src = ((const fvec4*)(ws + (size_t)g * npts * 8)) + (size_t)base * 2;
            #pragma unroll
            for (int pass = 0; pass < 2; ++pass) {
                int v = pass * 256 + tid;        // 512 fvec4 per group per block
                fvec4 d = src[v];                // lane-contiguous global read
                int pv = v >> 1;                 // local point row
                int c  = g * 2 + (v & 1);        // logical 16B chunk 0..7
                lt4[pv * 8 + (c ^ (pv & 7))] = d;   // XOR-swizzled, conflict-free
            }
        }
        __syncthreads();
        #pragma unroll
        for (int i = 0; i < 8; ++i) {
            int p  = i * 32 + (tid >> 3);        // local point row
            int cc = tid & 7;                    // logical chunk
            fvec4 r = lt4[p * 8 + (cc ^ (p & 7))];
            ((fvec4*)(out + (size_t)base * 32))[i * 256 + tid] = r;  // 1 KB/wave contiguous
        }
    } else {
        // tail block (tiny): direct per-point copy
        int p = base + tid;
        if (p < npts) {
            float* op = out + (size_t)p * 32;
            #pragma unroll
            for (int g = 0; g < 4; ++g) {
                const fvec4* s = (const fvec4*)(ws + ((size_t)g * npts + (size_t)p) * 8);
                *(fvec4*)(op + g * 8 + 0) = s[0];
                *(fvec4*)(op + g * 8 + 4) = s[1];
            }
        }
    }
}

// ---------------- Fallback: round-2 kernel (global gathers), used if ws too small
__global__ __launch_bounds__(256, 4) void hash4d_kernel(
    const float* __restrict__ coords,
    const float* __restrict__ tstamps,
    const float* __restrict__ tables,
    float* __restrict__ out,
    int npts, ResArr res)
{
    int n = blockIdx.x * blockDim.x + threadIdx.x;
    if (n >= npts) return;

    float x = coords[3 * n + 0];
    float y = coords[3 * n + 1];
    float z = coords[3 * n + 2];
    float t = tstamps[n];
    t = fminf(fmaxf(t, 0.0f), 1.0f);

    float c0 = (x + 50.0f) / 100.0f;
    float c1 = (y + 50.0f) / 100.0f;
    float c2 = (z + 50.0f) / 100.0f;
    float c3 = t;

    const unsigned P1 = 2654435761u, P2 = 805459861u, P3 = 3674653429u;
    float acc[32];

    #pragma unroll
    for (int L = 0; L < NL; ++L) {
        float rf = (float)res.r[L];
        float s0 = c0 * rf, s1 = c1 * rf, s2 = c2 * rf, s3 = c3 * rf;
        float g0 = floorf(s0), g1 = floorf(s1), g2 = floorf(s2), g3 = floorf(s3);
        float f0 = s0 - g0, f1 = s1 - g1, f2 = s2 - g2, f3 = s3 - g3;

        unsigned a0 = (unsigned)(int)g0;
        unsigned a1 = (unsigned)(int)g1 * P1;
        unsigned a2 = (unsigned)(int)g2 * P2;
        unsigned a3 = (unsigned)(int)g3 * P3;
        unsigned b0 = a0 + 1u, b1 = a1 + P1, b2 = a2 + P2, b3 = a3 + P3;

        float w0a = 1.0f - f0, w0b = f0;
        float w1a = 1.0f - f1, w1b = f1;
        float w2a = 1.0f - f2, w2b = f2;
        float w3a = 1.0f - f3, w3b = f3;

        const float2* tab = ((const float2*)tables) + (size_t)L * (size_t)HS;
        float A = 0.0f, B = 0.0f;
        #pragma unroll
        for (int ci = 0; ci < 16; ++ci) {
            unsigned h = ((ci & 1) ? b0 : a0) ^ ((ci & 2) ? b1 : a1) ^
                         ((ci & 4) ? b2 : a2) ^ ((ci & 8) ? b3 : a3);
            float2 fv = tab[h & (HS - 1)];
            float w = ((((ci & 1) ? w0b : w0a) * ((ci & 2) ? w1b : w1a)) *
                       ((ci & 4) ? w2b : w2a)) * ((ci & 8) ? w3b : w3a);
            A += w * fv.x;
            B += w * fv.y;
        }
        acc[2 * L + 0] = A;
        acc[2 * L + 1] = B;
    }

    float* op = out + (size_t)n * 32;
    #pragma unroll
    for (int i = 0; i < 8; ++i) {
        fvec4 v = { acc[4 * i + 0], acc[4 * i + 1],
                    acc[4 * i + 2], acc[4 * i + 3] };
        *(fvec4*)(op + 4 * i) = v;
    }
}

extern "C" void kernel_launch(void* const* d_in, const int* in_sizes, int n_in,
                              void* d_out, int out_size, void* d_ws, size_t ws_size,
                              hipStream_t stream) {
    const float* coords  = (const float*)d_in[0];
    const float* tstamps = (const float*)d_in[1];
    const float* tables  = (const float*)d_in[2];
    float* out = (float*)d_out;

    // resolutions computed host-side with the same double-precision exp/log as the
    // reference (keeps int() truncation bit-identical; do NOT hardcode)
    ResArr ra;
    for (int l = 0; l < 16; ++l) {
        double f = (double)l / 15.0;
        double v = exp(log(16.0) * (1.0 - f) + log(512.0) * f);
        ra.r[l] = (int)v;
    }

    int n = in_sizes[0] / 3;
    size_t need = (size_t)n * 32 * sizeof(float);

    if (ws_size >= need) {
        int ng = (n + TPB - 1) / TPB;
        if (ng > 256) ng = 256;
        if (ng < 1) ng = 1;
        hash4d_fused_kernel<<<ng, TPB, 0, stream>>>(
            coords, tstamps, tables, (float*)d_ws, n, ra);
        int nb = (n + 255) / 256;
        hash4d_out_kernel<<<nb, 256, 0, stream>>>((const float*)d_ws, out, n);
    } else {
        hash4d_kernel<<<(n + 255) / 256, 256, 0, stream>>>(
            coords, tstamps, tables, out, n, ra);
    }
}

// Round 3
// 694.682 us; speedup vs baseline: 1.2273x; 1.0998x over previous
//
#include <hip/hip_runtime.h>
#include <cmath>

#define HS 32768
#define NL 16
#define TPB 1024
#define PPT 8
#define CAP (TPB * PPT)

typedef float fvec4 __attribute__((ext_vector_type(4)));

struct ResArr { int r[16]; };

// Fused point-major kernel, direct-to-out.
// Key fix vs rounds 1/2: every global store INSTRUCTION fully tiles 32 B sectors.
// Evidence: per-instruction sector-split stores showed 2.08-2.17x WRITE_SIZE
// amplification; single-instruction sector-complete stores showed 1.0x.
// At each 4-level flush, a __shfl pair-transpose puts the two 16 B halves of
// point r's 32 B group record into lanes 2r/2r+1, so one dwordx4 store
// instruction covers whole sectors of out[N][32].
__global__ __launch_bounds__(TPB, 1) void hash4d_fused_kernel(
    const float* __restrict__ coords,
    const float* __restrict__ tstamps,
    const float* __restrict__ tables,
    float* __restrict__ out,
    int npts, ResArr res)
{
    __shared__ unsigned lds_tab[HS];   // 128 KB: two bf16 feats packed per entry

    const int chunk = (npts + (int)gridDim.x - 1) / (int)gridDim.x;
    const int wbase = (int)blockIdx.x * chunk;
    const int lim   = min(wbase + chunk, npts);
    const int tid   = (int)threadIdx.x;
    const int lane  = tid & 63;

    const unsigned P1 = 2654435761u, P2 = 805459861u, P3 = 3674653429u;
    const unsigned MASK4 = (HS - 1u) << 2;   // hash mask pre-shifted to byte offset

    for (int sbase = wbase; sbase < lim; sbase += CAP) {

        // ---- per-point invariants: computed ONCE, reused across all 16 levels ----
        float c0[PPT], c1[PPT], c2[PPT], c3[PPT];
        #pragma unroll
        for (int k = 0; k < PPT; ++k) {
            int p = sbase + k * TPB + tid;
            bool v = (p < lim);
            float x = 0.0f, y = 0.0f, z = 0.0f, t = 0.0f;
            if (v) {
                x = coords[3 * p + 0];
                y = coords[3 * p + 1];
                z = coords[3 * p + 2];
                t = tstamps[p];
            }
            t = fminf(fmaxf(t, 0.0f), 1.0f);
            // exact same arithmetic as reference (add, true divide) — amortized 16x
            c0[k] = (x + 50.0f) / 100.0f;
            c1[k] = (y + 50.0f) / 100.0f;
            c2[k] = (z + 50.0f) / 100.0f;
            c3[k] = t;
        }

        float acc[PPT][8];   // current group of 4 levels (static indexing only)

        #pragma unroll
        for (int L = 0; L < NL; ++L) {
            __syncthreads();   // all reads of previous table done before overwrite
            {   // stage table L: fvec4 loads (2 entries), pack bf16x2 (RNE), b64 writes
                const fvec4* gt = (const fvec4*)(tables + (size_t)L * HS * 2);
                #pragma unroll 4
                for (int j = tid; j < HS / 2; j += TPB) {
                    fvec4 v = gt[j];
                    unsigned u0 = __float_as_uint(v.x), u1 = __float_as_uint(v.y);
                    unsigned u2 = __float_as_uint(v.z), u3 = __float_as_uint(v.w);
                    unsigned r0 = u0 + 0x7fffu + ((u0 >> 16) & 1u);
                    unsigned r1 = u1 + 0x7fffu + ((u1 >> 16) & 1u);
                    unsigned r2 = u2 + 0x7fffu + ((u2 >> 16) & 1u);
                    unsigned r3 = u3 + 0x7fffu + ((u3 >> 16) & 1u);
                    uint2 pk;
                    pk.x = __builtin_amdgcn_perm(r1, r0, 0x07060302u);
                    pk.y = __builtin_amdgcn_perm(r3, r2, 0x07060302u);
                    *(uint2*)&lds_tab[2 * j] = pk;   // 8-aligned, 2-way bank (free)
                }
            }
            __syncthreads();

            const float rf = (float)res.r[L];
            const int g4 = L & 3;

            #pragma unroll
            for (int k = 0; k < PPT; ++k) {
                float s0 = c0[k] * rf, s1 = c1[k] * rf, s2 = c2[k] * rf, s3 = c3[k] * rf;
                float g0 = floorf(s0), g1 = floorf(s1), g2 = floorf(s2), g3 = floorf(s3);
                float f0 = s0 - g0, f1 = s1 - g1, f2 = s2 - g2, f3 = s3 - g3;

                // primes pre-shifted <<2: (x*P)<<2 == x*(P<<2) mod 2^32
                unsigned a0 = ((unsigned)(int)g0) << 2;
                unsigned a1 = (unsigned)(int)g1 * (P1 << 2);
                unsigned a2 = (unsigned)(int)g2 * (P2 << 2);
                unsigned a3 = (unsigned)(int)g3 * (P3 << 2);
                unsigned b0 = a0 + 4u;
                unsigned b1 = a1 + (P1 << 2);
                unsigned b2 = a2 + (P2 << 2);
                unsigned b3 = a3 + (P3 << 2);

                float m0 = 1.0f - f0, m1 = 1.0f - f1, m2 = 1.0f - f2, m3 = 1.0f - f3;
                float w01_0 = m0 * m1, w01_1 = f0 * m1, w01_2 = m0 * f1, w01_3 = f0 * f1;
                float w23_0 = m2 * m3, w23_1 = f2 * m3, w23_2 = m2 * f3, w23_3 = f2 * f3;

                float A = 0.0f, B = 0.0f;
                #pragma unroll
                for (int hi = 0; hi < 4; ++hi) {
                    unsigned hb = ((hi & 1) ? b2 : a2) ^ ((hi & 2) ? b3 : a3);
                    float whi = (hi == 0) ? w23_0 : (hi == 1) ? w23_1 : (hi == 2) ? w23_2 : w23_3;
                    float ax = 0.0f, ay = 0.0f;
                    #pragma unroll
                    for (int lo = 0; lo < 4; ++lo) {
                        unsigned off = (hb ^ ((lo & 1) ? b0 : a0) ^ ((lo & 2) ? b1 : a1)) & MASK4;
                        float wlo = (lo == 0) ? w01_0 : (lo == 1) ? w01_1 : (lo == 2) ? w01_2 : w01_3;
                        unsigned pk = *(const unsigned*)((const char*)lds_tab + off);
                        ax = fmaf(wlo, __uint_as_float(pk << 16), ax);
                        ay = fmaf(wlo, __uint_as_float(pk & 0xffff0000u), ay);
                    }
                    A = fmaf(whi, ax, A);
                    B = fmaf(whi, ay, B);
                }
                acc[k][2 * g4 + 0] = A;
                acc[k][2 * g4 + 1] = B;

                if (g4 == 3) {
                    // In-wave pair transpose: lanes 2r/2r+1 take halves 0/1 of
                    // point r's 8-float group record, then one dwordx4 store per
                    // instruction covers full 32 B sectors of out.
                    const int g = L >> 2;
                    const int wavept0 = sbase + k * TPB + (tid & ~63);
                    #pragma unroll
                    for (int m = 0; m < 2; ++m) {
                        int s = (lane >> 1) + 32 * m;       // source lane = point idx in wave
                        float q0l = __shfl(acc[k][0], s, 64);
                        float q0h = __shfl(acc[k][4], s, 64);
                        float q1l = __shfl(acc[k][1], s, 64);
                        float q1h = __shfl(acc[k][5], s, 64);
                        float q2l = __shfl(acc[k][2], s, 64);
                        float q2h = __shfl(acc[k][6], s, 64);
                        float q3l = __shfl(acc[k][3], s, 64);
                        float q3h = __shfl(acc[k][7], s, 64);
                        bool h = (lane & 1);
                        fvec4 v = { h ? q0h : q0l, h ? q1h : q1l,
                                    h ? q2h : q2l, h ? q3h : q3l };
                        int q = wavept0 + s;
                        if (q < lim) {
                            // byte addr = q*128 + g*32 + (lane&1)*16 — pair = full sector
                            *(fvec4*)(out + (size_t)q * 32 + g * 8 + (lane & 1) * 4) = v;
                        }
                    }
                }
            }
        }
    }
}

extern "C" void kernel_launch(void* const* d_in, const int* in_sizes, int n_in,
                              void* d_out, int out_size, void* d_ws, size_t ws_size,
                              hipStream_t stream) {
    const float* coords  = (const float*)d_in[0];
    const float* tstamps = (const float*)d_in[1];
    const float* tables  = (const float*)d_in[2];
    float* out = (float*)d_out;

    // resolutions computed host-side with the same double-precision exp/log as the
    // reference (keeps int() truncation bit-identical; do NOT hardcode)
    ResArr ra;
    for (int l = 0; l < 16; ++l) {
        double f = (double)l / 15.0;
        double v = exp(log(16.0) * (1.0 - f) + log(512.0) * f);
        ra.r[l] = (int)v;
    }

    int n = in_sizes[0] / 3;
    int ng = (n + TPB - 1) / TPB;
    if (ng > 256) ng = 256;   // 1 block/CU (128 KB LDS); more would serialize restaging
    if (ng < 1) ng = 1;

    hash4d_fused_kernel<<<ng, TPB, 0, stream>>>(coords, tstamps, tables, out, n, ra);
}